// Round 2
// baseline (686.090 us; speedup 1.0000x reference)
//
#include <hip/hip_runtime.h>

// VectorQuantizer: z (32,64,64,64) fp32, embedding_w (2048,64) fp32.
// Outputs concat: quantized_out (32,64,64,64) | indices (32,64,64) as float | loss (1)
//
// Numerics: bit-exact replication of the fp32 reference (verified prior rounds):
//   S_n = pairwise64(z_n^2), b_k = pairwise64(w_k^2)  (numpy pairwise_sum order)
//   C_nk = one sequential fp32 fused-FMA chain over c=0..63 ascending per (n,k)
//   d = fp32(fp32(S+b) - fp32(2C)), argmin first-index tie-break.
//   Here d = __builtin_fmaf(acc, -2.0f, Sb): 2*acc is exact in fp32 (exp+1),
//   so fma rounds the same exact value Sb - 2*acc once -> identical bits.
//
// R6: LDS-free main loop. One row per lane, z in 64 VGPRs (coalesced dword
// loads, no transpose, no barriers, no f2 unpack). w and bsum on the scalar
// pipe (s_load_dwordx4 -> SGPR operand of v_fma_f32). lgkmcnt now counts only
// s_loads. 4 waves/block = same 64 rows x disjoint 512-code ranges; 2048
// blocks; __launch_bounds__(256,5) caps VGPR at 102 -> 5 blocks/CU (20
// waves/CU). Argmin merged via packed-key LDS atomicMin (d>0, verified R3);
// wave 0 owns the epilogue (full row resident in its VGPRs).

#define KCODES   2048
#define CDIM     64
#define OUT_Q    0
#define OUT_IDX  8388608
#define OUT_LOSS 8519680

typedef unsigned long long u64;

__device__ __forceinline__ float fc(const float4& v, int i) {
    return i == 0 ? v.x : (i == 1 ? v.y : (i == 2 ? v.z : v.w));
}

__device__ __forceinline__ float pairwise64(const float a[64]) {
    float r[8];
#pragma unroll
    for (int j = 0; j < 8; ++j) r[j] = a[j];
#pragma unroll
    for (int m = 1; m < 8; ++m)
#pragma unroll
        for (int j = 0; j < 8; ++j) r[j] = __fadd_rn(r[j], a[m * 8 + j]);
    float s01 = __fadd_rn(r[0], r[1]);
    float s23 = __fadd_rn(r[2], r[3]);
    float s45 = __fadd_rn(r[4], r[5]);
    float s67 = __fadd_rn(r[6], r[7]);
    return __fadd_rn(__fadd_rn(s01, s23), __fadd_rn(s45, s67));
}

// ---------------- kernel A: b_k = pairwise64(w_k^2) ----------------
__global__ __launch_bounds__(256) void vq_bsum(const float* __restrict__ w,
                                               float* __restrict__ bsum) {
    int k = blockIdx.x * 256 + threadIdx.x;
    const float4* wr = (const float4*)(w + (size_t)k * CDIM);
    float a[64];
#pragma unroll
    for (int m = 0; m < 16; ++m) {
        float4 v = wr[m];
        a[4 * m + 0] = __fmul_rn(v.x, v.x);
        a[4 * m + 1] = __fmul_rn(v.y, v.y);
        a[4 * m + 2] = __fmul_rn(v.z, v.z);
        a[4 * m + 3] = __fmul_rn(v.w, v.w);
    }
    bsum[k] = pairwise64(a);
}

// ---------------- kernel B: main VQ ----------------
__global__ __launch_bounds__(256, 5) void vq_main(const float* __restrict__ z,
                                                  const float* __restrict__ w,
                                                  const float* __restrict__ bsum,
                                                  float* __restrict__ out,
                                                  double* __restrict__ partial) {
    __shared__ u64 skey[64];

    const int t  = threadIdx.x;
    const int l  = t & 63;                        // lane = row within block
    const int wv = t >> 6;                        // wave id 0..3
    const int bb = blockIdx.x;                    // 2048 blocks, 64 rows each
    const size_t zbase = (size_t)(bb >> 6) * 262144 + (size_t)(bb & 63) * 64;

    if (t < 64) skey[t] = 0xFFFFFFFFFFFFFFFFull;

    // ---- z row straight into registers (coalesced; replicated per wave) ----
    const float* zp = z + zbase + l;
    float zr[64];
#pragma unroll
    for (int c = 0; c < 64; ++c) zr[c] = zp[(size_t)c * 4096];

    // ---- S = numpy pairwise sum of squares (squares rounded separately) ----
    float r[8];
#pragma unroll
    for (int j = 0; j < 8; ++j) r[j] = __fmul_rn(zr[j], zr[j]);
#pragma unroll
    for (int m = 1; m < 8; ++m)
#pragma unroll
        for (int j = 0; j < 8; ++j)
            r[j] = __fadd_rn(r[j], __fmul_rn(zr[m * 8 + j], zr[m * 8 + j]));
    const float S = __fadd_rn(__fadd_rn(__fadd_rn(r[0], r[1]), __fadd_rn(r[2], r[3])),
                              __fadd_rn(__fadd_rn(r[4], r[5]), __fadd_rn(r[6], r[7])));

    __syncthreads();                              // skey init visible

    // ---- sweep this wave's 512 codes; all-uniform w/bsum -> s_load path ----
    const int kwave = __builtin_amdgcn_readfirstlane(wv) * 512;
    float dmin = __builtin_inff();
    unsigned int kmin = 0;

    for (int ks = 0; ks < 32; ++ks) {
        const int k0 = kwave + ks * 16;           // wave-uniform
        const float* wk = w + (size_t)k0 * CDIM;

        float acc[16];
#pragma unroll
        for (int j = 0; j < 16; ++j) acc[j] = 0.0f;

#pragma unroll
        for (int c0 = 0; c0 < 64; c0 += 4) {
#pragma unroll
            for (int j = 0; j < 16; ++j) {
                const float4 wc = *(const float4*)(wk + (size_t)(j * CDIM + c0));
                // dims ascending -> one sequential fused chain per (row, code)
                acc[j] = __builtin_fmaf(zr[c0 + 0], wc.x, acc[j]);
                acc[j] = __builtin_fmaf(zr[c0 + 1], wc.y, acc[j]);
                acc[j] = __builtin_fmaf(zr[c0 + 2], wc.z, acc[j]);
                acc[j] = __builtin_fmaf(zr[c0 + 3], wc.w, acc[j]);
            }
        }

        const float4 bq0 = *(const float4*)(bsum + k0);
        const float4 bq1 = *(const float4*)(bsum + k0 + 4);
        const float4 bq2 = *(const float4*)(bsum + k0 + 8);
        const float4 bq3 = *(const float4*)(bsum + k0 + 12);
#pragma unroll
        for (int j = 0; j < 16; ++j) {
            float bj = (j < 4) ? fc(bq0, j) : (j < 8) ? fc(bq1, j - 4)
                     : (j < 12) ? fc(bq2, j - 8) : fc(bq3, j - 12);
            float Sb = __fadd_rn(S, bj);
            float d  = __builtin_fmaf(acc[j], -2.0f, Sb);   // == round(Sb - 2*acc)
            if (d < dmin) { dmin = d; kmin = (unsigned int)(k0 + j); }
        }
    }

    // ---- merge per-row argmin across the 4 waves (d > 0; verified scheme) ----
    atomicMin(&skey[l], ((u64)__float_as_uint(dmin) << 32) | (u64)kmin);
    __syncthreads();

    if (wv != 0) return;

    // ---- epilogue on wave 0 (full row resident in zr) ----
    const unsigned int kq = (unsigned int)(skey[l] & 0xFFFFFFFFull);
    out[OUT_IDX + (size_t)bb * 64 + l] = (float)kq;

    const float* wq = w + (size_t)kq * CDIM;
    double lacc = 0.0;
#pragma unroll
    for (int c0 = 0; c0 < 64; c0 += 4) {
        const float4 q4 = *(const float4*)(wq + c0);
#pragma unroll
        for (int i = 0; i < 4; ++i) {
            float q  = fc(q4, i);
            float zv = zr[c0 + i];
            float d1  = __fsub_rn(q, zv);         // quantized - zp
            float val = __fadd_rn(zv, d1);        // zp + (q - zp)
            out[OUT_Q + zbase + (size_t)(c0 + i) * 4096 + l] = val;
            lacc += (double)__fmul_rn(d1, d1);
        }
    }

#pragma unroll
    for (int off = 1; off < 64; off <<= 1) lacc += __shfl_xor(lacc, off, 64);
    if (l == 0) partial[bb] = lacc;
}

// ---------------- kernel C: reduce loss partials (2048 doubles) ----------------
__global__ __launch_bounds__(256) void vq_loss(const double* __restrict__ partial,
                                               float* __restrict__ out) {
    int t = threadIdx.x;
    double s = 0.0;
#pragma unroll
    for (int i = 0; i < 8; ++i) s += partial[t + i * 256];
#pragma unroll
    for (int off = 1; off < 64; off <<= 1) s += __shfl_xor(s, off, 64);
    __shared__ double sr[4];
    if ((t & 63) == 0) sr[t >> 6] = s;
    __syncthreads();
    if (t == 0)
        out[OUT_LOSS] = (float)((sr[0] + sr[1] + sr[2] + sr[3]) * (0.25 / 8388608.0));
}

extern "C" void kernel_launch(void* const* d_in, const int* in_sizes, int n_in,
                              void* d_out, int out_size, void* d_ws, size_t ws_size,
                              hipStream_t stream) {
    (void)in_sizes; (void)n_in; (void)out_size; (void)ws_size;
    const float* z = (const float*)d_in[0];
    const float* w = (const float*)d_in[1];
    float* out     = (float*)d_out;

    float*  bsum    = (float*)d_ws;                  // 2048 floats (8 KB)
    double* partial = (double*)((char*)d_ws + 8192); // 2048 doubles (16 KB)

    vq_bsum<<<8, 256, 0, stream>>>(w, bsum);
    vq_main<<<2048, 256, 0, stream>>>(z, w, bsum, out, partial);
    vq_loss<<<1, 256, 0, stream>>>(partial, out);
}